// Round 9
// baseline (232.878 us; speedup 1.0000x reference)
//
#include <hip/hip_runtime.h>
#include <hip/hip_bf16.h>

// Gram matrix: G = X @ X^T, X = [512, 65536] fp32, out = [512, 512] fp32.
// Round 19: r18 (ws epilogue) = 90.4us gram / 227.9 bench, best. Delivery
// model refit across r1..r18: B/cyc/CU tracks INDEPENDENT RESIDENT LOAD
// STREAMS, not bytes: r16 1blk/CU=3.9, r10/r17/r18 2-2.5blk=8.8-9.3,
// r15 uniform=10.0, r1 oversubscribed=12.9. Byte cuts at fixed structure
// bought nothing (r17: -5% bytes -> -1.7us). Current cap = grid: 640/256
// = 2.5 blocks/CU (LDS would allow 7, VGPR=64 allows 8 waves/SIMD).
// This round: ONE change -- split K finer. KC=512, 128 chunks/tile,
// grid 1280: ~5 resident blocks/CU, barrier phases staggered, port fed
// through every block's compute phase. Engine byte-for-byte r18.
//   - ws 84 MB (1280 slabs); guarded fallback to r18's 640-grid (42 MB),
//     then to the atomic path. reduce sums 128 partials, 320x128 threads
//     (all CUs active; r18's 160x256 left 96 CUs idle).
// Pre-committed: if occupancy rises but gram stays >=88us, ~9.3 B/cyc is
// the engine ceiling -> declare roofline.
// History: r1 1.07GB 135us (12.9 B/cyc); r10 100; r11 100; r12 117(R);
// r13 126(R); r14 131(R); r15 109(R); r16 112(R); r17 98.3; r18 90.4.

typedef short bf16x8 __attribute__((ext_vector_type(8)));   // 8 bf16 = 4 VGPRs
typedef float f32x4  __attribute__((ext_vector_type(4)));   // MFMA acc

#define HW    65536
#define CDIM  512
#define LDSS  40            // panel stride in shorts (r10 proven)
#define TILE_ELEMS 16384    // 128*128

__device__ __forceinline__ short f2bf(float f) {
    __hip_bfloat16 h = __float2bfloat16(f);   // RNE
    short s;
    __builtin_memcpy(&s, &h, sizeof(short));
    return s;
}

__device__ __forceinline__ bf16x8 cvt8(float4 a, float4 b) {
    bf16x8 v;
    v[0] = f2bf(a.x); v[1] = f2bf(a.y); v[2] = f2bf(a.z); v[3] = f2bf(a.w);
    v[4] = f2bf(b.x); v[5] = f2bf(b.y); v[6] = f2bf(b.z); v[7] = f2bf(b.w);
    return v;
}

// CSH = log2(chunks per tile): 7 (KC=512, grid 1280) or 6 (KC=1024, grid 640).
// USE_WS=1: store partial tile to workspace slab; USE_WS=0: atomic path.
template <int CSH, int USE_WS>
__global__ __launch_bounds__(256, 2)
void gram_kernel(const float* __restrict__ X, float* __restrict__ out,
                 float* __restrict__ ws) {
    constexpr int CHUNKS = 1 << CSH;
    constexpr int KC     = HW >> CSH;       // 512 or 1024
    constexpr int ITERS  = KC / 32;         // 16 or 32
    // decode (tile-major, upper tiles first -- they are the long blocks):
    //   p < 6*CHUNKS  -> upper tile o = p>>CSH (0..5)
    //   p >= 6*CHUNKS -> diag tile (p-6*CHUNKS)>>CSH (0..3)
    // chunk = p & (CHUNKS-1) for both (6*CHUNKS is CHUNKS-aligned).
    const int p = blockIdx.x;
    int ti, tj;
    if (p < 6 * CHUNKS) {
        const int o = p >> CSH;
        const int TI[6] = {0, 0, 0, 1, 1, 2};
        const int TJ[6] = {1, 2, 3, 2, 3, 3};
        ti = TI[o]; tj = TJ[o];
    } else {
        ti = tj = (p - 6 * CHUNKS) >> CSH;
    }
    const int kbase = (p & (CHUNKS - 1)) * KC;
    const bool diag = (ti == tj);

    __shared__ short As[128 * LDSS];
    __shared__ short Bs[128 * LDSS];

    const int t    = threadIdx.x;
    const int wave = t >> 6;
    const int lane = t & 63;
    const int wm   = wave & 1;          // 2x2 wave grid, each wave = 64x64
    const int wn   = wave >> 1;

    // --- staging mapping (r10's): 2 threads per row, 16 consecutive fp32 ---
    const int srow  = t >> 1;           // 0..127
    const int shalf = (t & 1) * 16;     // k offset 0 or 16
    const float* pa = X + (size_t)(ti * 128 + srow) * HW + kbase + shalf;
    const float* pb = X + (size_t)(tj * 128 + srow) * HW + kbase + shalf;
    short* wa = As + srow * LDSS + shalf;
    short* wb = Bs + srow * LDSS + shalf;

    // --- fragment read offsets (A-operand: m = lane&15, k-group = lane>>4) ---
    const int fm = lane & 15;
    const int kg = lane >> 4;           // 0..3, each group = 8 contiguous k
    int a_off[4], b_off[4];
#pragma unroll
    for (int i = 0; i < 4; ++i) {
        a_off[i] = (wm * 64 + i * 16 + fm) * LDSS + kg * 8;
        b_off[i] = (wn * 64 + i * 16 + fm) * LDSS + kg * 8;
    }
    const short* Bbase = diag ? As : Bs;   // diag: B frags read the A panel

    f32x4 acc[4][4];
#pragma unroll
    for (int i = 0; i < 4; ++i)
#pragma unroll
        for (int j = 0; j < 4; ++j)
            acc[i][j] = (f32x4){0.f, 0.f, 0.f, 0.f};

    for (int it = 0; it < ITERS; ++it) {
        // global fp32 loads (16 floats per panel row-half; diag: A only)
        float4 a0 = *(const float4*)(pa + 0);
        float4 a1 = *(const float4*)(pa + 4);
        float4 a2 = *(const float4*)(pa + 8);
        float4 a3 = *(const float4*)(pa + 12);
        float4 b0, b1, b2, b3;
        if (!diag) {
            b0 = *(const float4*)(pb + 0);
            b1 = *(const float4*)(pb + 4);
            b2 = *(const float4*)(pb + 8);
            b3 = *(const float4*)(pb + 12);
        }

        bf16x8 va0 = cvt8(a0, a1), va1 = cvt8(a2, a3);
        bf16x8 vb0, vb1;
        if (!diag) { vb0 = cvt8(b0, b1); vb1 = cvt8(b2, b3); }

        __syncthreads();   // prior iteration's LDS reads complete
        *(bf16x8*)(wa + 0) = va0;
        *(bf16x8*)(wa + 8) = va1;
        if (!diag) {
            *(bf16x8*)(wb + 0) = vb0;
            *(bf16x8*)(wb + 8) = vb1;
        }
        __syncthreads();   // stage visible to all waves

        bf16x8 af[4], bfr[4];
#pragma unroll
        for (int i = 0; i < 4; ++i) af[i]  = *(const bf16x8*)(As + a_off[i]);
#pragma unroll
        for (int j = 0; j < 4; ++j) bfr[j] = *(const bf16x8*)(Bbase + b_off[j]);

#pragma unroll
        for (int i = 0; i < 4; ++i)
#pragma unroll
            for (int j = 0; j < 4; ++j)
                acc[i][j] = __builtin_amdgcn_mfma_f32_16x16x32_bf16(
                    af[i], bfr[j], acc[i][j], 0, 0, 0);

        pa += 32;
        pb += 32;
    }

    // --- epilogue ---
    // C/D layout (verified m89/m91): col = lane&15, row = (lane>>4)*4 + reg
    if (USE_WS) {
        // contention-free streaming stores into this block's private slab
        float* slab = ws + (size_t)p * TILE_ELEMS;
        const int lrow0 = wm * 64 + (lane >> 4) * 4;
        const int lcol0 = wn * 64 + fm;
#pragma unroll
        for (int i = 0; i < 4; ++i)
#pragma unroll
            for (int j = 0; j < 4; ++j)
#pragma unroll
                for (int r = 0; r < 4; ++r)
                    slab[(lrow0 + i * 16 + r) * 128 + lcol0 + j * 16] =
                        acc[i][j][r];
    } else {
        const int orow0 = ti * 128 + wm * 64 + (lane >> 4) * 4;
        const int ocol0 = tj * 128 + wn * 64 + fm;
#pragma unroll
        for (int i = 0; i < 4; ++i)
#pragma unroll
            for (int j = 0; j < 4; ++j)
#pragma unroll
                for (int r = 0; r < 4; ++r)
                    atomicAdd(out + (orow0 + i * 16 + r) * CDIM + ocol0 + j * 16,
                              acc[i][j][r]);
    }
}

// ------- reduce: sum CHUNKS chunk-partials per tile element, write out + mirror -------
// 40960 threads as 320 blocks x 128 (all 256 CUs active; r18's 160x256 left
// 96 CUs idle). Thread = one float4 of one of the 10 unique tiles.
template <int CSH>
__global__ __launch_bounds__(128)
void reduce_kernel(const float* __restrict__ ws, float* __restrict__ out) {
    constexpr int CHUNKS = 1 << CSH;
    const int gid = blockIdx.x * 128 + threadIdx.x;    // 0..40959
    const int tt  = gid >> 12;                         // tile 0..9
    const int e4  = (gid & 4095) << 2;                 // element base 0..16380
    const int TI[10] = {0, 0, 0, 1, 1, 2, 0, 1, 2, 3};
    const int TJ[10] = {1, 2, 3, 2, 3, 3, 0, 1, 2, 3};
    const int ti = TI[tt], tj = TJ[tt];
    // slab base: upper tile tt at p=tt*CHUNKS; diag at 6*CHUNKS+(tt-6)*CHUNKS
    // -> both equal tt*CHUNKS.
    const float* base = ws + ((size_t)tt << CSH) * TILE_ELEMS + e4;

    f32x4 s0 = {0.f, 0.f, 0.f, 0.f}, s1 = s0, s2 = s0, s3 = s0;
#pragma unroll 4
    for (int c = 0; c < CHUNKS; c += 4) {  // 4 independent chains (MLP)
        s0 += *(const f32x4*)(base + (size_t)(c + 0) * TILE_ELEMS);
        s1 += *(const f32x4*)(base + (size_t)(c + 1) * TILE_ELEMS);
        s2 += *(const f32x4*)(base + (size_t)(c + 2) * TILE_ELEMS);
        s3 += *(const f32x4*)(base + (size_t)(c + 3) * TILE_ELEMS);
    }
    const f32x4 s = (s0 + s1) + (s2 + s3);

    const int r0 = e4 >> 7;                // row in tile 0..127
    const int c0 = e4 & 127;               // col base in tile
    // main write (coalesced float4)
    *(f32x4*)(out + (ti * 128 + r0) * CDIM + tj * 128 + c0) = s;
    // mirror for upper tiles (transposed scalar stores)
    if (tt < 6) {
#pragma unroll
        for (int k = 0; k < 4; ++k)
            out[(tj * 128 + c0 + k) * CDIM + ti * 128 + r0] = s[k];
    }
}

// ---------------- fallback mirror (atomic path only) ----------------
__global__ __launch_bounds__(256)
void mirror_kernel(float* __restrict__ out) {
    const int id = blockIdx.x * 256 + threadIdx.x;   // 0..262143
    const int r = id >> 9;
    const int c = id & 511;
    if ((r >> 7) > (c >> 7))          // 128-grain tiles
        out[id] = out[c * CDIM + r];
}

extern "C" void kernel_launch(void* const* d_in, const int* in_sizes, int n_in,
                              void* d_out, int out_size, void* d_ws, size_t ws_size,
                              hipStream_t stream) {
    const float* x = (const float*)d_in[0];
    float* out = (float*)d_out;
    const size_t ws128 = 1280ull * TILE_ELEMS * sizeof(float);  // 83.9 MB
    const size_t ws64  =  640ull * TILE_ELEMS * sizeof(float);  // 41.9 MB

    if (d_ws != nullptr && ws_size >= ws128) {
        float* ws = (float*)d_ws;
        gram_kernel<7, 1><<<dim3(1280), dim3(256), 0, stream>>>(x, out, ws);
        reduce_kernel<7><<<dim3(320), dim3(128), 0, stream>>>(ws, out);
    } else if (d_ws != nullptr && ws_size >= ws64) {
        // r18's proven path
        float* ws = (float*)d_ws;
        gram_kernel<6, 1><<<dim3(640), dim3(256), 0, stream>>>(x, out, ws);
        reduce_kernel<6><<<dim3(320), dim3(128), 0, stream>>>(ws, out);
    } else {
        // fallback: r17's proven atomic path
        hipMemsetAsync(d_out, 0, (size_t)out_size * sizeof(float), stream);
        gram_kernel<6, 0><<<dim3(640), dim3(256), 0, stream>>>(x, out, nullptr);
        mirror_kernel<<<dim3(1024), dim3(256), 0, stream>>>(out);
    }
}